// Round 1
// baseline (787.593 us; speedup 1.0000x reference)
//
#include <hip/hip_runtime.h>
#include <math.h>

// Layout: H = 64 features, N = 50000 nodes, E = 1.6M edges.
// d_out = [ new_mean (N*64) | new_std (N*64) | total_kl (1) ]
// d_ws  = [ h_m (N*64) | h_s (N*64) ]

__global__ __launch_bounds__(256) void k_init_out(float* __restrict__ om,
                                                  float* __restrict__ olv,
                                                  const float* __restrict__ bm,
                                                  const float* __restrict__ bs,
                                                  int total) {
    int i = blockIdx.x * 256 + threadIdx.x;
    if (i < total) {
        int f = i & 63;
        om[i]  = bm[f];   // new_mean accumulator starts at bias
        olv[i] = bs[f];   // log-var accumulator starts at bias
    }
}

// Fused: h_m = mean @ Wm ; h_s = (std*std) @ Ws. Weights in LDS, row values
// broadcast across the wave via __shfl (lane f holds element f of the row).
__global__ __launch_bounds__(256) void k_gemm2(const float* __restrict__ mean,
                                               const float* __restrict__ stdv,
                                               const float* __restrict__ Wm,
                                               const float* __restrict__ Ws,
                                               float* __restrict__ hm,
                                               float* __restrict__ hs, int n) {
    __shared__ float sWm[64][64];
    __shared__ float sWs[64][64];
    for (int i = threadIdx.x; i < 64 * 64; i += 256) {
        sWm[i >> 6][i & 63] = Wm[i];
        sWs[i >> 6][i & 63] = Ws[i];
    }
    __syncthreads();
    const int f = threadIdx.x & 63;      // feature/output column
    const int wave = threadIdx.x >> 6;   // 0..3
    const int ROWS = 64;                 // rows per block
    int base = blockIdx.x * ROWS;
    for (int r = wave; r < ROWS; r += 4) {
        int row = base + r;
        if (row >= n) return;
        float mv = mean[row * 64 + f];
        float sv = stdv[row * 64 + f];
        float vv = sv * sv;
        float accm = 0.f, accs = 0.f;
#pragma unroll
        for (int k = 0; k < 64; ++k) {
            float a = __shfl(mv, k, 64);
            float b = __shfl(vv, k, 64);
            accm += a * sWm[k][f];
            accs += b * sWs[k][f];
        }
        hm[row * 64 + f] = accm;
        hs[row * 64 + f] = accs;
    }
}

// One lane per (edge, feature): gather h[src], scale, scatter-add to out[dst].
// Both GCNs fused: mean uses w, log-var uses w*w.
__global__ __launch_bounds__(256) void k_scatter(const int* __restrict__ ei,
                                                 const float* __restrict__ ew,
                                                 const float* __restrict__ hm,
                                                 const float* __restrict__ hs,
                                                 float* __restrict__ om,
                                                 float* __restrict__ olv, int E) {
    int t = blockIdx.x * 256 + threadIdx.x;
    int e = t >> 6;
    if (e >= E) return;
    int f = t & 63;
    int src = ei[e];
    int dst = ei[E + e];
    float w = ew[e];
    float m = hm[src * 64 + f];
    float v = hs[src * 64 + f];
    atomicAdd(&om[dst * 64 + f], m * w);
    atomicAdd(&olv[dst * 64 + f], v * (w * w));
}

// In-place: new_std = sqrt(exp(log_var) + 1e-6)
__global__ __launch_bounds__(256) void k_finalize(float* __restrict__ olv, int total) {
    int i = blockIdx.x * 256 + threadIdx.x;
    if (i < total) {
        float x = olv[i];
        olv[i] = sqrtf(expf(x) + 1e-6f);
    }
}

// total_kl = KL(Wm) + KL(Ws); 2*4096 elements, one block.
__global__ __launch_bounds__(256) void k_kl(const float* __restrict__ Wm_mu,
                                            const float* __restrict__ Wm_ls,
                                            const float* __restrict__ Ws_mu,
                                            const float* __restrict__ Ws_ls,
                                            float* __restrict__ out) {
    __shared__ float red[256];
    const float C = -2.3025850929940457f - 0.5f;  // log(0.1) - 0.5
    float acc = 0.f;
    for (int i = threadIdx.x; i < 4096; i += 256) {
        {
            float mu = Wm_mu[i], ls = Wm_ls[i];
            float s = expf(ls);
            acc += C - ls + (s * s + mu * mu) * 50.0f;  // 1/(2*0.1^2) = 50
        }
        {
            float mu = Ws_mu[i], ls = Ws_ls[i];
            float s = expf(ls);
            acc += C - ls + (s * s + mu * mu) * 50.0f;
        }
    }
    red[threadIdx.x] = acc;
    __syncthreads();
    for (int s = 128; s > 0; s >>= 1) {
        if (threadIdx.x < s) red[threadIdx.x] += red[threadIdx.x + s];
        __syncthreads();
    }
    if (threadIdx.x == 0) out[0] = red[0];
}

extern "C" void kernel_launch(void* const* d_in, const int* in_sizes, int n_in,
                              void* d_out, int out_size, void* d_ws, size_t ws_size,
                              hipStream_t stream) {
    const float* mean  = (const float*)d_in[0];
    const float* stdv  = (const float*)d_in[1];
    const int*   ei    = (const int*)d_in[2];
    const float* ew    = (const float*)d_in[3];
    const float* Wm_mu = (const float*)d_in[4];
    const float* Wm_ls = (const float*)d_in[5];
    const float* bm    = (const float*)d_in[6];
    const float* Ws_mu = (const float*)d_in[7];
    const float* Ws_ls = (const float*)d_in[8];
    const float* bs    = (const float*)d_in[9];

    const int n = in_sizes[0] / 64;   // 50000 nodes
    const int E = in_sizes[3];        // 1600000 edges
    const int total = n * 64;

    float* om  = (float*)d_out;       // new_mean
    float* olv = om + total;          // log-var accumulator -> new_std in place
    float* okl = om + 2 * total;      // total_kl scalar

    float* hm = (float*)d_ws;         // h_m
    float* hs = hm + total;           // h_s

    k_init_out<<<(total + 255) / 256, 256, 0, stream>>>(om, olv, bm, bs, total);
    k_gemm2<<<(n + 63) / 64, 256, 0, stream>>>(mean, stdv, Wm_mu, Ws_mu, hm, hs, n);

    long long tthreads = (long long)E * 64;
    int sblocks = (int)((tthreads + 255) / 256);
    k_scatter<<<sblocks, 256, 0, stream>>>(ei, ew, hm, hs, om, olv, E);

    k_finalize<<<(total + 255) / 256, 256, 0, stream>>>(olv, total);
    k_kl<<<1, 256, 0, stream>>>(Wm_mu, Wm_ls, Ws_mu, Ws_ls, okl);
}

// Round 2
// 457.819 us; speedup vs baseline: 1.7203x; 1.7203x over previous
//
#include <hip/hip_runtime.h>
#include <math.h>

// H = 64 features, N = 50000 nodes, E = 1.6M edges.
// d_out = [ new_mean (N*64) | new_std (N*64) | total_kl (1) ]
//
// Strategy: counting-sort edges by dst into a CSR (per-call, stateless), then
// one wave per node gathers+accumulates (no data atomics), then the 64x64
// transform is applied per-row in the same kernel (aggregation and the linear
// transform commute), fusing bias + sqrt(exp(x)+1e-6).
//
// ws layout (ints):
//   [0, NP)         counts
//   [NP, 2NP)       offsets (CSR row starts)
//   [2NP, 3NP)      cursor  (scatter write positions)
//   [3NP, 3NP+256)  partials (scan block sums)
//   [3NP+256, ...)  erec: E x int2 {src, bitcast(w)}

#define NBLK_SCAN 196            // 196*256 = 50176 >= 50000
#define NP (NBLK_SCAN * 256)

__global__ __launch_bounds__(256) void k_hist(const int* __restrict__ ei,
                                              int* __restrict__ counts, int E) {
    int t = blockIdx.x * 256 + threadIdx.x;
    if (t < E) atomicAdd(&counts[ei[E + t]], 1);
}

__global__ __launch_bounds__(256) void k_scan_block(const int* __restrict__ counts,
                                                    int* __restrict__ offsets,
                                                    int* __restrict__ partials) {
    __shared__ int s[256];
    int i = blockIdx.x * 256 + threadIdx.x;
    int v = counts[i];
    s[threadIdx.x] = v;
    __syncthreads();
    for (int off = 1; off < 256; off <<= 1) {
        int t = 0;
        if (threadIdx.x >= off) t = s[threadIdx.x - off];
        __syncthreads();
        s[threadIdx.x] += t;
        __syncthreads();
    }
    offsets[i] = s[threadIdx.x] - v;           // exclusive
    if (threadIdx.x == 255) partials[blockIdx.x] = s[255];
}

__global__ __launch_bounds__(256) void k_scan_part(int* __restrict__ partials) {
    __shared__ int s[256];
    int v = (threadIdx.x < NBLK_SCAN) ? partials[threadIdx.x] : 0;
    s[threadIdx.x] = v;
    __syncthreads();
    for (int off = 1; off < 256; off <<= 1) {
        int t = 0;
        if (threadIdx.x >= off) t = s[threadIdx.x - off];
        __syncthreads();
        s[threadIdx.x] += t;
        __syncthreads();
    }
    partials[threadIdx.x] = s[threadIdx.x] - v;  // exclusive
}

__global__ __launch_bounds__(256) void k_scan_add(int* __restrict__ offsets,
                                                  const int* __restrict__ partials,
                                                  int* __restrict__ cursor) {
    int i = blockIdx.x * 256 + threadIdx.x;
    int o = offsets[i] + partials[blockIdx.x];
    offsets[i] = o;
    cursor[i] = o;
}

__global__ __launch_bounds__(256) void k_scatter_edges(const int* __restrict__ ei,
                                                       const float* __restrict__ ew,
                                                       int* __restrict__ cursor,
                                                       int2* __restrict__ erec, int E) {
    int t = blockIdx.x * 256 + threadIdx.x;
    if (t >= E) return;
    int src = ei[t];
    int dst = ei[E + t];
    float w = ew[t];
    int pos = atomicAdd(&cursor[dst], 1);
    erec[pos] = make_int2(src, __float_as_int(w));
}

// One wave per node: gather-accumulate over its CSR edge list, then the
// 64x64 transform for its row (shfl-broadcast GEMM, W in LDS), then the
// epilogue. Writes final outputs directly.
__global__ __launch_bounds__(256) void k_aggregate(const float* __restrict__ mean,
                                                   const float* __restrict__ stdv,
                                                   const int* __restrict__ offsets,
                                                   const int* __restrict__ counts,
                                                   const int2* __restrict__ erec,
                                                   const float* __restrict__ Wm,
                                                   const float* __restrict__ Ws,
                                                   const float* __restrict__ bm,
                                                   const float* __restrict__ bs,
                                                   float* __restrict__ om,
                                                   float* __restrict__ os, int n) {
    __shared__ float sWm[64][64];
    __shared__ float sWs[64][64];
    for (int i = threadIdx.x; i < 4096; i += 256) {
        sWm[i >> 6][i & 63] = Wm[i];
        sWs[i >> 6][i & 63] = Ws[i];
    }
    __syncthreads();

    int node = blockIdx.x * 4 + (threadIdx.x >> 6);
    if (node >= n) return;
    int lane = threadIdx.x & 63;
    int start = offsets[node];
    int cnt = counts[node];

    float accm = 0.f, accs = 0.f;
    for (int base = 0; base < cnt; base += 64) {
        int m = cnt - base;
        if (m > 64) m = 64;
        int2 er = make_int2(0, 0);
        if (lane < m) er = erec[start + base + lane];
        for (int j = 0; j < m; ++j) {
            int src = __shfl(er.x, j, 64);
            float w = __int_as_float(__shfl(er.y, j, 64));
            float mv = mean[src * 64 + lane];
            float sv = stdv[src * 64 + lane];
            accm += w * mv;
            accs += (w * w) * (sv * sv);
        }
    }

    // Row transform: lane holds agg element 'lane'; compute output col = lane.
    float am = 0.f, as_ = 0.f;
#pragma unroll
    for (int k = 0; k < 64; ++k) {
        float a = __shfl(accm, k, 64);
        float b = __shfl(accs, k, 64);
        am  += a * sWm[k][lane];
        as_ += b * sWs[k][lane];
    }
    om[node * 64 + lane] = am + bm[lane];
    float lv = as_ + bs[lane];
    os[node * 64 + lane] = sqrtf(expf(lv) + 1e-6f);
}

// total_kl = KL(Wm) + KL(Ws); 2*4096 elements, one block.
__global__ __launch_bounds__(256) void k_kl(const float* __restrict__ Wm_mu,
                                            const float* __restrict__ Wm_ls,
                                            const float* __restrict__ Ws_mu,
                                            const float* __restrict__ Ws_ls,
                                            float* __restrict__ out) {
    __shared__ float red[256];
    const float C = -2.3025850929940457f - 0.5f;  // log(0.1) - 0.5
    float acc = 0.f;
    for (int i = threadIdx.x; i < 4096; i += 256) {
        {
            float mu = Wm_mu[i], ls = Wm_ls[i];
            float s = expf(ls);
            acc += C - ls + (s * s + mu * mu) * 50.0f;  // 1/(2*0.1^2) = 50
        }
        {
            float mu = Ws_mu[i], ls = Ws_ls[i];
            float s = expf(ls);
            acc += C - ls + (s * s + mu * mu) * 50.0f;
        }
    }
    red[threadIdx.x] = acc;
    __syncthreads();
    for (int s = 128; s > 0; s >>= 1) {
        if (threadIdx.x < s) red[threadIdx.x] += red[threadIdx.x + s];
        __syncthreads();
    }
    if (threadIdx.x == 0) out[0] = red[0];
}

extern "C" void kernel_launch(void* const* d_in, const int* in_sizes, int n_in,
                              void* d_out, int out_size, void* d_ws, size_t ws_size,
                              hipStream_t stream) {
    const float* mean  = (const float*)d_in[0];
    const float* stdv  = (const float*)d_in[1];
    const int*   ei    = (const int*)d_in[2];
    const float* ew    = (const float*)d_in[3];
    const float* Wm_mu = (const float*)d_in[4];
    const float* Wm_ls = (const float*)d_in[5];
    const float* bm    = (const float*)d_in[6];
    const float* Ws_mu = (const float*)d_in[7];
    const float* Ws_ls = (const float*)d_in[8];
    const float* bs    = (const float*)d_in[9];

    const int n = in_sizes[0] / 64;   // 50000
    const int E = in_sizes[3];        // 1600000
    const int total = n * 64;

    float* om  = (float*)d_out;
    float* os  = om + total;
    float* okl = om + 2 * total;

    int* counts   = (int*)d_ws;
    int* offsets  = counts + NP;
    int* cursor   = offsets + NP;
    int* partials = cursor + NP;
    int2* erec    = (int2*)(partials + 256);   // byte offset 603136, 8B-aligned

    hipMemsetAsync(counts, 0, NP * sizeof(int), stream);
    k_hist<<<(E + 255) / 256, 256, 0, stream>>>(ei, counts, E);
    k_scan_block<<<NBLK_SCAN, 256, 0, stream>>>(counts, offsets, partials);
    k_scan_part<<<1, 256, 0, stream>>>(partials);
    k_scan_add<<<NBLK_SCAN, 256, 0, stream>>>(offsets, partials, cursor);
    k_scatter_edges<<<(E + 255) / 256, 256, 0, stream>>>(ei, ew, cursor, erec, E);
    k_aggregate<<<(n + 3) / 4, 256, 0, stream>>>(mean, stdv, offsets, counts, erec,
                                                 Wm_mu, Ws_mu, bm, bs, om, os, n);
    k_kl<<<1, 256, 0, stream>>>(Wm_mu, Wm_ls, Ws_mu, Ws_ls, okl);
}

// Round 3
// 350.523 us; speedup vs baseline: 2.2469x; 1.3061x over previous
//
#include <hip/hip_runtime.h>
#include <math.h>

// H = 64 features, N = 50000 nodes, E = 1.6M edges.
// d_out = [ new_mean (N*64) | new_std (N*64) | total_kl (1) ]
//
// Pipeline: counting-sort edges by dst into CSR (stateless per call), then
// one wave per node gathers+accumulates with 4 edges x float4-features in
// flight, then per-row 64x64 transform (aggregation commutes with the linear
// transform), fused bias + sqrt(exp(x)+1e-6) epilogue.
//
// ws layout (ints):
//   [0, NP)         counts
//   [NP, 2NP)       offsets (CSR row starts)
//   [2NP, 3NP)      cursor  (scatter write positions)
//   [3NP, 3NP+256)  partials (scan block sums)
//   [3NP+256, ...)  erec: E x int2 {src, bitcast(w)}

#define NBLK_SCAN 196            // 196*256 = 50176 >= 50000
#define NP (NBLK_SCAN * 256)

__global__ __launch_bounds__(256) void k_hist(const int* __restrict__ ei,
                                              int* __restrict__ counts, int E) {
    int t = blockIdx.x * 256 + threadIdx.x;
    if (t < E) atomicAdd(&counts[ei[E + t]], 1);
}

__global__ __launch_bounds__(256) void k_scan_block(const int* __restrict__ counts,
                                                    int* __restrict__ offsets,
                                                    int* __restrict__ partials) {
    __shared__ int s[256];
    int i = blockIdx.x * 256 + threadIdx.x;
    int v = counts[i];
    s[threadIdx.x] = v;
    __syncthreads();
    for (int off = 1; off < 256; off <<= 1) {
        int t = 0;
        if (threadIdx.x >= off) t = s[threadIdx.x - off];
        __syncthreads();
        s[threadIdx.x] += t;
        __syncthreads();
    }
    offsets[i] = s[threadIdx.x] - v;           // exclusive
    if (threadIdx.x == 255) partials[blockIdx.x] = s[255];
}

__global__ __launch_bounds__(256) void k_scan_part(int* __restrict__ partials) {
    __shared__ int s[256];
    int v = (threadIdx.x < NBLK_SCAN) ? partials[threadIdx.x] : 0;
    s[threadIdx.x] = v;
    __syncthreads();
    for (int off = 1; off < 256; off <<= 1) {
        int t = 0;
        if (threadIdx.x >= off) t = s[threadIdx.x - off];
        __syncthreads();
        s[threadIdx.x] += t;
        __syncthreads();
    }
    partials[threadIdx.x] = s[threadIdx.x] - v;  // exclusive
}

__global__ __launch_bounds__(256) void k_scan_add(int* __restrict__ offsets,
                                                  const int* __restrict__ partials,
                                                  int* __restrict__ cursor) {
    int i = blockIdx.x * 256 + threadIdx.x;
    int o = offsets[i] + partials[blockIdx.x];
    offsets[i] = o;
    cursor[i] = o;
}

__global__ __launch_bounds__(256) void k_scatter_edges(const int* __restrict__ ei,
                                                       const float* __restrict__ ew,
                                                       int* __restrict__ cursor,
                                                       int2* __restrict__ erec, int E) {
    int t = blockIdx.x * 256 + threadIdx.x;
    if (t >= E) return;
    int src = ei[t];
    int dst = ei[E + t];
    float w = ew[t];
    int pos = atomicAdd(&cursor[dst], 1);
    erec[pos] = make_int2(src, __float_as_int(w));
}

// One wave per node (grid-strided). Wave = 4 edge-groups x 16 lanes; each lane
// loads a float4 (4 features). 16 edges in flight per unrolled iteration.
__global__ __launch_bounds__(256) void k_aggregate(const float* __restrict__ mean,
                                                   const float* __restrict__ stdv,
                                                   const int* __restrict__ offsets,
                                                   const int* __restrict__ counts,
                                                   const int2* __restrict__ erec,
                                                   const float* __restrict__ Wm,
                                                   const float* __restrict__ Ws,
                                                   const float* __restrict__ bm,
                                                   const float* __restrict__ bs,
                                                   float* __restrict__ om,
                                                   float* __restrict__ os, int n) {
    __shared__ float sWm[64][64];
    __shared__ float sWs[64][64];
    for (int i = threadIdx.x; i < 4096; i += 256) {
        sWm[i >> 6][i & 63] = Wm[i];
        sWs[i >> 6][i & 63] = Ws[i];
    }
    __syncthreads();

    const int lane = threadIdx.x & 63;
    const int wid  = threadIdx.x >> 6;
    const int g    = lane >> 4;     // edge subgroup 0..3
    const int f4   = lane & 15;     // feature quad: features f4*4 .. f4*4+3

    for (int node = blockIdx.x * 4 + wid; node < n; node += gridDim.x * 4) {
        const int start = offsets[node];
        const int cnt   = counts[node];

        float4 accm = {0.f, 0.f, 0.f, 0.f};
        float4 accs = {0.f, 0.f, 0.f, 0.f};

        for (int base = 0; base < cnt; base += 64) {
            int m = cnt - base;
            if (m > 64) m = 64;
            int2 er = make_int2(0, 0);              // w = 0.0f for tail lanes
            if (lane < m) er = erec[start + base + lane];
            int mr = (m + 15) & ~15;                // round to 16 (4 per group)

            for (int j0 = 0; j0 < mr; j0 += 16) {
                int j;
                j = j0 + g;
                int   s0 = __shfl(er.x, j, 64);
                float w0 = __int_as_float(__shfl(er.y, j, 64));
                j = j0 + 4 + g;
                int   s1 = __shfl(er.x, j, 64);
                float w1 = __int_as_float(__shfl(er.y, j, 64));
                j = j0 + 8 + g;
                int   s2 = __shfl(er.x, j, 64);
                float w2 = __int_as_float(__shfl(er.y, j, 64));
                j = j0 + 12 + g;
                int   s3 = __shfl(er.x, j, 64);
                float w3 = __int_as_float(__shfl(er.y, j, 64));

                const float4 m0 = *(const float4*)(mean + (size_t)s0 * 64 + f4 * 4);
                const float4 v0 = *(const float4*)(stdv + (size_t)s0 * 64 + f4 * 4);
                const float4 m1 = *(const float4*)(mean + (size_t)s1 * 64 + f4 * 4);
                const float4 v1 = *(const float4*)(stdv + (size_t)s1 * 64 + f4 * 4);
                const float4 m2 = *(const float4*)(mean + (size_t)s2 * 64 + f4 * 4);
                const float4 v2 = *(const float4*)(stdv + (size_t)s2 * 64 + f4 * 4);
                const float4 m3 = *(const float4*)(mean + (size_t)s3 * 64 + f4 * 4);
                const float4 v3 = *(const float4*)(stdv + (size_t)s3 * 64 + f4 * 4);

                accm.x += w0 * m0.x; accm.y += w0 * m0.y; accm.z += w0 * m0.z; accm.w += w0 * m0.w;
                accm.x += w1 * m1.x; accm.y += w1 * m1.y; accm.z += w1 * m1.z; accm.w += w1 * m1.w;
                accm.x += w2 * m2.x; accm.y += w2 * m2.y; accm.z += w2 * m2.z; accm.w += w2 * m2.w;
                accm.x += w3 * m3.x; accm.y += w3 * m3.y; accm.z += w3 * m3.z; accm.w += w3 * m3.w;

                float q0 = w0 * w0, q1 = w1 * w1, q2 = w2 * w2, q3 = w3 * w3;
                accs.x += q0 * v0.x * v0.x; accs.y += q0 * v0.y * v0.y;
                accs.z += q0 * v0.z * v0.z; accs.w += q0 * v0.w * v0.w;
                accs.x += q1 * v1.x * v1.x; accs.y += q1 * v1.y * v1.y;
                accs.z += q1 * v1.z * v1.z; accs.w += q1 * v1.w * v1.w;
                accs.x += q2 * v2.x * v2.x; accs.y += q2 * v2.y * v2.y;
                accs.z += q2 * v2.z * v2.z; accs.w += q2 * v2.w * v2.w;
                accs.x += q3 * v3.x * v3.x; accs.y += q3 * v3.y * v3.y;
                accs.z += q3 * v3.z * v3.z; accs.w += q3 * v3.w * v3.w;
            }
        }

        // Reduce across the 4 edge-groups (lanes differing in bits 4,5).
        accm.x += __shfl_xor(accm.x, 16, 64); accm.x += __shfl_xor(accm.x, 32, 64);
        accm.y += __shfl_xor(accm.y, 16, 64); accm.y += __shfl_xor(accm.y, 32, 64);
        accm.z += __shfl_xor(accm.z, 16, 64); accm.z += __shfl_xor(accm.z, 32, 64);
        accm.w += __shfl_xor(accm.w, 16, 64); accm.w += __shfl_xor(accm.w, 32, 64);
        accs.x += __shfl_xor(accs.x, 16, 64); accs.x += __shfl_xor(accs.x, 32, 64);
        accs.y += __shfl_xor(accs.y, 16, 64); accs.y += __shfl_xor(accs.y, 32, 64);
        accs.z += __shfl_xor(accs.z, 16, 64); accs.z += __shfl_xor(accs.z, 32, 64);
        accs.w += __shfl_xor(accs.w, 16, 64); accs.w += __shfl_xor(accs.w, 32, 64);
        // Now lane (g, f4) holds the full sums for features f4*4..f4*4+3
        // (replicated across the 4 groups) -> agg[k] lives in lane k>>2, comp k&3.

        float am = 0.f, as_ = 0.f;
#pragma unroll
        for (int k = 0; k < 64; ++k) {
            const int sl = k >> 2;
            float ca = ((k & 3) == 0) ? accm.x : ((k & 3) == 1) ? accm.y
                     : ((k & 3) == 2) ? accm.z : accm.w;
            float cb = ((k & 3) == 0) ? accs.x : ((k & 3) == 1) ? accs.y
                     : ((k & 3) == 2) ? accs.z : accs.w;
            float a = __shfl(ca, sl, 64);
            float b = __shfl(cb, sl, 64);
            am  += a * sWm[k][lane];
            as_ += b * sWs[k][lane];
        }
        om[node * 64 + lane] = am + bm[lane];
        float lv = as_ + bs[lane];
        os[node * 64 + lane] = sqrtf(expf(lv) + 1e-6f);
    }
}

// total_kl = KL(Wm) + KL(Ws); 2*4096 elements, one block.
__global__ __launch_bounds__(256) void k_kl(const float* __restrict__ Wm_mu,
                                            const float* __restrict__ Wm_ls,
                                            const float* __restrict__ Ws_mu,
                                            const float* __restrict__ Ws_ls,
                                            float* __restrict__ out) {
    __shared__ float red[256];
    const float C = -2.3025850929940457f - 0.5f;  // log(0.1) - 0.5
    float acc = 0.f;
    for (int i = threadIdx.x; i < 4096; i += 256) {
        {
            float mu = Wm_mu[i], ls = Wm_ls[i];
            float s = expf(ls);
            acc += C - ls + (s * s + mu * mu) * 50.0f;  // 1/(2*0.1^2) = 50
        }
        {
            float mu = Ws_mu[i], ls = Ws_ls[i];
            float s = expf(ls);
            acc += C - ls + (s * s + mu * mu) * 50.0f;
        }
    }
    red[threadIdx.x] = acc;
    __syncthreads();
    for (int s = 128; s > 0; s >>= 1) {
        if (threadIdx.x < s) red[threadIdx.x] += red[threadIdx.x + s];
        __syncthreads();
    }
    if (threadIdx.x == 0) out[0] = red[0];
}

extern "C" void kernel_launch(void* const* d_in, const int* in_sizes, int n_in,
                              void* d_out, int out_size, void* d_ws, size_t ws_size,
                              hipStream_t stream) {
    const float* mean  = (const float*)d_in[0];
    const float* stdv  = (const float*)d_in[1];
    const int*   ei    = (const int*)d_in[2];
    const float* ew    = (const float*)d_in[3];
    const float* Wm_mu = (const float*)d_in[4];
    const float* Wm_ls = (const float*)d_in[5];
    const float* bm    = (const float*)d_in[6];
    const float* Ws_mu = (const float*)d_in[7];
    const float* Ws_ls = (const float*)d_in[8];
    const float* bs    = (const float*)d_in[9];

    const int n = in_sizes[0] / 64;   // 50000
    const int E = in_sizes[3];        // 1600000
    const int total = n * 64;

    float* om  = (float*)d_out;
    float* os  = om + total;
    float* okl = om + 2 * total;

    int* counts   = (int*)d_ws;
    int* offsets  = counts + NP;
    int* cursor   = offsets + NP;
    int* partials = cursor + NP;
    int2* erec    = (int2*)(partials + 256);

    hipMemsetAsync(counts, 0, NP * sizeof(int), stream);
    k_hist<<<(E + 255) / 256, 256, 0, stream>>>(ei, counts, E);
    k_scan_block<<<NBLK_SCAN, 256, 0, stream>>>(counts, offsets, partials);
    k_scan_part<<<1, 256, 0, stream>>>(partials);
    k_scan_add<<<NBLK_SCAN, 256, 0, stream>>>(offsets, partials, cursor);
    k_scatter_edges<<<(E + 255) / 256, 256, 0, stream>>>(ei, ew, cursor, erec, E);
    k_aggregate<<<1280, 256, 0, stream>>>(mean, stdv, offsets, counts, erec,
                                          Wm_mu, Ws_mu, bm, bs, om, os, n);
    k_kl<<<1, 256, 0, stream>>>(Wm_mu, Wm_ls, Ws_mu, Ws_ls, okl);
}

// Round 4
// 331.483 us; speedup vs baseline: 2.3760x; 1.0574x over previous
//
#include <hip/hip_runtime.h>
#include <hip/hip_fp16.h>
#include <math.h>

// H = 64 features, N = 50000 nodes, E = 1.6M edges.
// d_out = [ new_mean (N*64) | new_std (N*64) | total_kl (1) ]
//
// Pipeline:
//   1. counting-sort edges by dst into CSR (esrc + fp16 weight arrays)
//   2. pack mean/var rows into one fp16 array, 256 B/node:
//      16 chunks of 16 B, chunk c: type t=c&1 (0=mean,1=var), octet o=c>>1,
//      uint j of chunk holds features 8o+2j (lo half) and 8o+2j+1 (hi half)
//   3. aggregate: wave/node, 4 edge-groups x 16 lanes, lane16 = chunk id;
//      8 edges in flight per group-iter; f32 accumulate; then the 64x64
//      transform in-wave (aggregation commutes with the linear map), fused
//      bias + sqrt(exp(x)+1e-6) epilogue.
//
// ws (ints unless noted): counts/cursor [NP] | offsets [NP+16] | partials [256]
//                         | esrc [E] | ewh ushort[E] | pk uint[n*64] (16B-aligned)

#define NBLK_SCAN 196            // 196*256 = 50176 >= 50000
#define NP (NBLK_SCAN * 256)

__global__ __launch_bounds__(256) void k_hist(const int* __restrict__ ei,
                                              int* __restrict__ counts, int E) {
    int t = blockIdx.x * 256 + threadIdx.x;
    if (t < E) atomicAdd(&counts[ei[E + t]], 1);
}

__global__ __launch_bounds__(256) void k_scan_block(const int* __restrict__ counts,
                                                    int* __restrict__ offsets,
                                                    int* __restrict__ partials) {
    __shared__ int s[256];
    int i = blockIdx.x * 256 + threadIdx.x;
    int v = counts[i];
    s[threadIdx.x] = v;
    __syncthreads();
    for (int off = 1; off < 256; off <<= 1) {
        int t = 0;
        if (threadIdx.x >= off) t = s[threadIdx.x - off];
        __syncthreads();
        s[threadIdx.x] += t;
        __syncthreads();
    }
    offsets[i] = s[threadIdx.x] - v;           // exclusive
    if (threadIdx.x == 255) partials[blockIdx.x] = s[255];
}

__global__ __launch_bounds__(256) void k_scan_part(int* __restrict__ partials) {
    __shared__ int s[256];
    int v = (threadIdx.x < NBLK_SCAN) ? partials[threadIdx.x] : 0;
    s[threadIdx.x] = v;
    __syncthreads();
    for (int off = 1; off < 256; off <<= 1) {
        int t = 0;
        if (threadIdx.x >= off) t = s[threadIdx.x - off];
        __syncthreads();
        s[threadIdx.x] += t;
        __syncthreads();
    }
    partials[threadIdx.x] = s[threadIdx.x] - v;  // exclusive
}

__global__ __launch_bounds__(256) void k_scan_add(int* __restrict__ offsets,
                                                  const int* __restrict__ partials,
                                                  int* __restrict__ cursor) {
    int i = blockIdx.x * 256 + threadIdx.x;
    int o = offsets[i] + partials[blockIdx.x];
    offsets[i] = o;
    cursor[i] = o;
}

__global__ __launch_bounds__(256) void k_scatter_edges(const int* __restrict__ ei,
                                                       const float* __restrict__ ew,
                                                       int* __restrict__ cursor,
                                                       int* __restrict__ esrc,
                                                       ushort* __restrict__ ewh, int E) {
    int t = blockIdx.x * 256 + threadIdx.x;
    if (t >= E) return;
    int src = ei[t];
    int dst = ei[E + t];
    float w = ew[t];
    int pos = atomicAdd(&cursor[dst], 1);
    esrc[pos] = src;
    ewh[pos] = __half_as_ushort(__float2half(w));   // RNE
}

// Build pk[node][64 uints]: chunk c = q>>2 (t=c&1, o=c>>1), uint j = q&3
// holds fp16(features 8o+2j, 8o+2j+1) of mean (t=0) or var=std^2 (t=1).
__global__ __launch_bounds__(256) void k_pack(const float* __restrict__ mean,
                                              const float* __restrict__ stdv,
                                              uint* __restrict__ pk, int n) {
    int tid = blockIdx.x * 256 + threadIdx.x;
    if (tid >= n * 64) return;
    int node = tid >> 6, q = tid & 63;
    int c = q >> 2, j = q & 3;
    int t = c & 1, o = c >> 1;
    int f0 = 8 * o + 2 * j;
    const float* src = t ? stdv : mean;
    float2 v = *reinterpret_cast<const float2*>(src + (size_t)node * 64 + f0);
    float a = v.x, b = v.y;
    if (t) { a = a * a; b = b * b; }
    __half2 h2 = __floats2half2_rn(a, b);           // .x = a (low half)
    pk[tid] = *reinterpret_cast<uint*>(&h2);
}

// One wave per node (grid-strided over 1280 blocks x 4 waves).
__global__ __launch_bounds__(256) void k_aggregate(const uint* __restrict__ pk,
                                                   const int* __restrict__ offsets,
                                                   const int* __restrict__ esrc,
                                                   const ushort* __restrict__ ewh,
                                                   const float* __restrict__ Wm,
                                                   const float* __restrict__ Ws,
                                                   const float* __restrict__ bm,
                                                   const float* __restrict__ bs,
                                                   float* __restrict__ om,
                                                   float* __restrict__ os, int n) {
    __shared__ float sWm[64][64];
    __shared__ float sWs[64][64];
    for (int i = threadIdx.x; i < 4096; i += 256) {
        sWm[i >> 6][i & 63] = Wm[i];
        sWs[i >> 6][i & 63] = Ws[i];
    }
    __syncthreads();

    const int lane = threadIdx.x & 63;
    const int wid  = threadIdx.x >> 6;
    const int g    = lane >> 4;      // edge subgroup 0..3
    const int l16  = lane & 15;      // chunk id: t = l16&1 (mean/var), o = l16>>1
    const int t    = l16 & 1;
    const float bmv = bm[lane];
    const float bsv = bs[lane];

    for (int node = blockIdx.x * 4 + wid; node < n; node += gridDim.x * 4) {
        const int start = offsets[node];
        const int cnt   = offsets[node + 1] - start;

        float acc[8] = {0.f, 0.f, 0.f, 0.f, 0.f, 0.f, 0.f, 0.f};

        for (int base = 0; base < cnt; base += 64) {
            int m = cnt - base;
            if (m > 64) m = 64;
            int es = 0, wb = 0;                    // fp16 0x0000 == 0.0f
            if (lane < m) {
                es = esrc[start + base + lane];
                wb = ewh[start + base + lane];
            }
            int mr = (m + 31) & ~31;               // 32 or 64

            for (int j0 = 0; j0 < mr; j0 += 32) {
                int   srcs[8];
                float wls[8];
#pragma unroll
                for (int u = 0; u < 8; ++u) {
                    int j = j0 + 4 * u + g;
                    srcs[u] = __shfl(es, j, 64);
                    int w16 = __shfl(wb, j, 64);
                    float w = __half2float(__ushort_as_half((ushort)w16));
                    wls[u] = t ? w * w : w;
                }
                uint4 dd[8];
#pragma unroll
                for (int u = 0; u < 8; ++u)
                    dd[u] = *reinterpret_cast<const uint4*>(
                        pk + (size_t)srcs[u] * 64 + l16 * 4);
#pragma unroll
                for (int u = 0; u < 8; ++u) {
                    float wl = wls[u];
#pragma unroll
                    for (int jj = 0; jj < 4; ++jj) {
                        uint u32 = (jj == 0) ? dd[u].x : (jj == 1) ? dd[u].y
                                 : (jj == 2) ? dd[u].z : dd[u].w;
                        __half2 h2 = *reinterpret_cast<__half2*>(&u32);
                        float2 f = __half22float2(h2);
                        acc[2 * jj]     += wl * f.x;
                        acc[2 * jj + 1] += wl * f.y;
                    }
                }
            }
        }

        // Reduce across the 4 edge-groups (bits 4,5 of lane).
#pragma unroll
        for (int c = 0; c < 8; ++c) {
            acc[c] += __shfl_xor(acc[c], 16, 64);
            acc[c] += __shfl_xor(acc[c], 32, 64);
        }
        // Lane l16 now holds (replicated over groups): acc[c] = aggregated
        // feature 8*(l16>>1)+c of type l16&1 (0=mean, 1=var).

        float am = 0.f, as_ = 0.f;
#pragma unroll
        for (int k = 0; k < 64; ++k) {
            float a = __shfl(acc[k & 7], (k >> 3) * 2, 64);       // mean lane
            float b = __shfl(acc[k & 7], (k >> 3) * 2 + 1, 64);   // var lane
            am  += a * sWm[k][lane];
            as_ += b * sWs[k][lane];
        }
        om[(size_t)node * 64 + lane] = am + bmv;
        float lv = as_ + bsv;
        os[(size_t)node * 64 + lane] = sqrtf(expf(lv) + 1e-6f);
    }
}

// total_kl = KL(Wm) + KL(Ws); 2*4096 elements, one block.
__global__ __launch_bounds__(256) void k_kl(const float* __restrict__ Wm_mu,
                                            const float* __restrict__ Wm_ls,
                                            const float* __restrict__ Ws_mu,
                                            const float* __restrict__ Ws_ls,
                                            float* __restrict__ out) {
    __shared__ float red[256];
    const float C = -2.3025850929940457f - 0.5f;  // log(0.1) - 0.5
    float acc = 0.f;
    for (int i = threadIdx.x; i < 4096; i += 256) {
        {
            float mu = Wm_mu[i], ls = Wm_ls[i];
            float s = expf(ls);
            acc += C - ls + (s * s + mu * mu) * 50.0f;  // 1/(2*0.1^2) = 50
        }
        {
            float mu = Ws_mu[i], ls = Ws_ls[i];
            float s = expf(ls);
            acc += C - ls + (s * s + mu * mu) * 50.0f;
        }
    }
    red[threadIdx.x] = acc;
    __syncthreads();
    for (int s = 128; s > 0; s >>= 1) {
        if (threadIdx.x < s) red[threadIdx.x] += red[threadIdx.x + s];
        __syncthreads();
    }
    if (threadIdx.x == 0) out[0] = red[0];
}

extern "C" void kernel_launch(void* const* d_in, const int* in_sizes, int n_in,
                              void* d_out, int out_size, void* d_ws, size_t ws_size,
                              hipStream_t stream) {
    const float* mean  = (const float*)d_in[0];
    const float* stdv  = (const float*)d_in[1];
    const int*   ei    = (const int*)d_in[2];
    const float* ew    = (const float*)d_in[3];
    const float* Wm_mu = (const float*)d_in[4];
    const float* Wm_ls = (const float*)d_in[5];
    const float* bm    = (const float*)d_in[6];
    const float* Ws_mu = (const float*)d_in[7];
    const float* Ws_ls = (const float*)d_in[8];
    const float* bs    = (const float*)d_in[9];

    const int n = in_sizes[0] / 64;   // 50000
    const int E = in_sizes[3];        // 1600000
    const int total = n * 64;

    float* om  = (float*)d_out;
    float* os  = om + total;
    float* okl = om + 2 * total;

    // ws carve-up (see header comment); pk 16B-aligned.
    char* wsb = (char*)d_ws;
    int* counts   = (int*)wsb;                 // doubles as cursor after scan
    int* offsets  = counts + NP;
    int* partials = offsets + NP + 16;
    int* esrc     = partials + 256;
    ushort* ewh   = (ushort*)(esrc + E);
    size_t pk_off = ((size_t)((char*)(ewh + E) - wsb) + 15) & ~(size_t)15;
    uint* pk      = (uint*)(wsb + pk_off);
    // footprint: ~22.8 MB (ws proven >= 25.6 MB in round 1)

    hipMemsetAsync(counts, 0, NP * sizeof(int), stream);
    k_hist<<<(E + 255) / 256, 256, 0, stream>>>(ei, counts, E);
    k_scan_block<<<NBLK_SCAN, 256, 0, stream>>>(counts, offsets, partials);
    k_scan_part<<<1, 256, 0, stream>>>(partials);
    k_scan_add<<<NBLK_SCAN, 256, 0, stream>>>(offsets, partials, counts);
    k_scatter_edges<<<(E + 255) / 256, 256, 0, stream>>>(ei, ew, counts, esrc, ewh, E);
    k_pack<<<(total + 255) / 256, 256, 0, stream>>>(mean, stdv, pk, n);
    k_aggregate<<<1280, 256, 0, stream>>>(pk, offsets, esrc, ewh,
                                          Wm_mu, Ws_mu, bm, bs, om, os, n);
    k_kl<<<1, 256, 0, stream>>>(Wm_mu, Wm_ls, Ws_mu, Ws_ls, okl);
}